// Round 13
// baseline (1424.199 us; speedup 1.0000x reference)
//
#include <hip/hip_runtime.h>
#include <hip/hip_bf16.h>

// SrnmSpmm: out[b,s,n] = sum_k x[b,s,keep[k]] * values[n,k] + bias[n]
// keep: cols {8i, 8i+2} of D_IN=4096 -> K=1024. M = B*S = 16384, N = 4096.
//
// R13: FUSED kernel. 256 blocks x 640 thr (10 waves, 128 KiB LDS, 1/CU):
// waves 0-7 = R11's 32x32-MFMA persistent GEMM (schedule unchanged; vmcnt
// is wave-local so prep waves don't perturb it); waves 8-9 = prep waves that
// match every barrier by construction and stream next-round A-panel
// compaction (x f32 -> xg bf16) in per-gap quanta. Round-0 A + all B built
// in an all-wave co-op phase first (~20 us). Cross-block sync: device-scope
// release/acquire flags in ws, zeroed per call via hipMemsetAsync.

#define KDIM    1024
#define NDIM    4096

typedef unsigned short u16;
typedef unsigned int   u32;
typedef __bf16 bf16x8 __attribute__((ext_vector_type(8)));
typedef float  f32x4  __attribute__((ext_vector_type(4)));
typedef float  f32x16 __attribute__((ext_vector_type(16)));

typedef const void __attribute__((address_space(1)))* gp_t;
typedef void __attribute__((address_space(3)))*       lp_t;

__device__ __forceinline__ u16 f2bf(float f) {
    u32 u = __float_as_uint(f);
    u += 0x7FFFu + ((u >> 16) & 1u);   // round-to-nearest-even
    return (u16)(u >> 16);
}
__device__ __forceinline__ u32 pack2(float a, float b) {
    return (u32)f2bf(a) | ((u32)f2bf(b) << 16);
}
#define NTLD(p) __builtin_nontemporal_load(p)

// ---- GEMM fragment/LDS macros (verbatim from R11, verified) ----
#define LDSA(d, kh) (((d) * 2 + (kh)) * 16384)
#define LDSB(d, kh) (65536 + ((d) * 2 + (kh)) * 16384)

#define LOADA(d, kh, mh) { _Pragma("unroll") \
    for (int mm = 0; mm < 2; ++mm) { _Pragma("unroll") \
    for (int ks = 0; ks < 2; ++ks) \
        af[mm * 2 + ks] = *(const bf16x8*)(lds + LDSA(d, kh) \
            + (wr * 8 + ((mh) * 2 + mm) * 2) * 1024 + fl_base \
            + (((ks << 5) + acol) ^ aswz)); } }

#define LOADB(d, kh) { _Pragma("unroll") \
    for (int nn = 0; nn < 2; ++nn) { _Pragma("unroll") \
    for (int ks = 0; ks < 2; ++ks) \
        bfr[nn * 2 + ks] = *(const bf16x8*)(lds + LDSB(d, kh) \
            + (wc * 4 + nn * 2) * 1024 + fl_base \
            + (((ks << 5) + acol) ^ aswz)); } }

#define MFMA8(mh) { \
    __builtin_amdgcn_s_setprio(1); \
    _Pragma("unroll") for (int mm = 0; mm < 2; ++mm) \
    _Pragma("unroll") for (int nn = 0; nn < 2; ++nn) \
    _Pragma("unroll") for (int ks = 0; ks < 2; ++ks) \
        acc[(mh) * 2 + mm][nn] = __builtin_amdgcn_mfma_f32_32x32x16_bf16( \
            af[mm * 2 + ks], bfr[nn * 2 + ks], acc[(mh) * 2 + mm][nn], 0, 0, 0); \
    __builtin_amdgcn_s_setprio(0); }

#define BAR() __builtin_amdgcn_s_barrier()
#define VMCNT6() asm volatile("s_waitcnt vmcnt(6)" ::: "memory")
#define VMCNT0() asm volatile("s_waitcnt vmcnt(0)" ::: "memory")

// ---- prep quantum: gap G (0..95) of round r produces set(r+1) ----
// 1M uint2 per round-set; (block, prep-thread pt, op k): u = bb*4096+k*128+pt
// -> set-row j=u>>8, li=u&255 -> panel p = 8*(j>>9)+((j>>8)&1)+2*(r+1).
// op m = G%3: 0: pa=x[..], 1: pb=x[..+8], 2: store packed uint2.
#define POP(G) { if ((G) < 96 && r < 3) { \
    const int k_ = (G) / 3, m_ = (G) % 3; \
    const int u_ = bb * 4096 + k_ * 128 + pt; \
    const int j_ = u_ >> 8, li_ = u_ & 255; \
    const int p_ = 8 * (j_ >> 9) + ((j_ >> 8) & 1) + 2 * (r + 1); \
    const size_t xr_ = (size_t)(256 * p_ + (j_ & 255)); \
    if (m_ == 0)      pa = NTLD((const f32x4*)(x + xr_ * 4096 + li_ * 16)); \
    else if (m_ == 1) pb = NTLD((const f32x4*)(x + xr_ * 4096 + li_ * 16 + 8)); \
    else xg2[xr_ * 256 + li_] = make_uint2(pack2(pa.x, pa.z), pack2(pb.x, pb.z)); \
} }

// ---- role-split phase: barriers in SHARED code (matched by construction) --
#define PH(RD, MH, G) { if (gw) { RD } else { POP(G); } BAR(); \
    if (gw) { MFMA8(MH); } else { POP((G) + 1); } BAR(); }
#define PHV(RD, MH, G) { if (gw) { RD } else { POP(G); } BAR(); \
    if (gw) { MFMA8(MH); VMCNT6(); } else { POP((G) + 1); } BAR(); }

#define ITERF(Ss, Sb, PI) { \
  PH (LOADB(0,0); LOADA(0,0,0); STAGE(Ss,(Sb)+0);, 0, (PI)*16+0) \
  PH (LOADA(0,0,1);             STAGE(Ss,(Sb)+1);, 1, (PI)*16+2) \
  PH (LOADB(0,1); LOADA(0,1,0); STAGE(Ss,(Sb)+2);, 0, (PI)*16+4) \
  PHV(LOADA(0,1,1);             STAGE(Ss,(Sb)+3);, 1, (PI)*16+6) \
  PH (LOADB(1,0); LOADA(1,0,0); STAGE(Ss,(Sb)+4);, 0, (PI)*16+8) \
  PH (LOADA(1,0,1);             STAGE(Ss,(Sb)+5);, 1, (PI)*16+10) \
  PH (LOADB(1,1); LOADA(1,1,0); STAGE(Ss,(Sb)+6);, 0, (PI)*16+12) \
  PHV(LOADA(1,1,1);             STAGE(Ss,(Sb)+7);, 1, (PI)*16+14) }

__global__ __launch_bounds__(640, 1) void fused_kernel(
    const float* __restrict__ x, const float* __restrict__ vals,
    const float* __restrict__ bias, u16* __restrict__ xg,
    u16* __restrict__ vb, u32* __restrict__ flags, float* __restrict__ C)
{
    __shared__ __align__(1024) char lds[131072];

    const int tid  = threadIdx.x;
    const int lane = tid & 63;
    const int wid  = tid >> 6;          // 0..9
    const bool gw  = (wid < 8);         // wave-uniform role
    const int pt   = tid - 512;         // prep thread index (valid when !gw)
    const int wr   = wid >> 2;
    const int wc   = wid & 3;
    const int bb   = blockIdx.x;        // 256 blocks, 1/CU (128 KiB LDS)

    uint2* xg2 = (uint2*)xg;
    uint4* vb4 = (uint4*)vb;

    // ---------- STAGE I: co-op prep of ALL B + round-0 A (all waves) -------
    {
        int i = bb * 640 + tid;
        for (; i < 524288; i += 163840) {            // vb: 4096x1024 bf16
            const f32x4* p = (const f32x4*)(vals + (size_t)i * 8);
            f32x4 a = NTLD(p), b = NTLD(p + 1);
            vb4[i] = make_uint4(pack2(a.x, a.y), pack2(a.z, a.w),
                                pack2(b.x, b.y), pack2(b.z, b.w));
        }
        i = bb * 640 + tid;
        for (; i < 1048576; i += 163840) {           // A set 0: panels 8c+e
            const int j = i >> 8, li = i & 255;
            const int p_ = 8 * (j >> 9) + ((j >> 8) & 1);
            const size_t xr = (size_t)(256 * p_ + (j & 255));
            const f32x4* q = (const f32x4*)(x + xr * 4096 + li * 16);
            f32x4 a = NTLD(q), b = NTLD(q + 2);
            xg2[xr * 256 + li] = make_uint2(pack2(a.x, a.z), pack2(b.x, b.z));
        }
    }
    __threadfence();
    __syncthreads();
    if (tid == 0) {
        __hip_atomic_fetch_add(&flags[0], 1u, __ATOMIC_RELEASE, __HIP_MEMORY_SCOPE_AGENT);
        while (__hip_atomic_load(&flags[0], __ATOMIC_ACQUIRE, __HIP_MEMORY_SCOPE_AGENT) < 256u)
            __builtin_amdgcn_s_sleep(8);
    }
    __syncthreads();
    __threadfence();

    // ---------- STAGE II: persistent GEMM (waves 0-7) + prep (waves 8-9) ---
    const int btm0 = (bb & 7) * 8 + (bb >> 7);
    const int btn  = (bb >> 3) & 15;

    const int st_r0 = (tid & 511) >> 2;   // staging pattern over 512 gemm thr
    const int st_ck = (((tid & 511) & 3) * 8) ^ ((tid & 32) >> 1) ^ ((tid & 64) >> 3);
    const u16* A0  = xg + (size_t)(btm0 * 256 + st_r0) * KDIM + st_ck;
    const u16* Bs0 = vb + (size_t)(btn  * 256 + st_r0) * KDIM + st_ck;
    const int dst0 = (tid & 511) * 16;

    const int fl_base = (lane & 15) * 64 + ((lane >> 4) & 1) * 1024;
    const int aswz    = (((lane >> 3) & 1) << 5) ^ (((lane >> 4) & 1) << 4);
    const int acol    = ((lane >> 5) & 1) * 16;

    auto STAGE = [&](const u16* as_, int s) {
        const int kt = s >> 2, j = s & 3;
        const int d = kt & 1, kh = (j >> 1) & 1;
        const int ko = kt * 64 + kh * 32;
        const u16* src = (j & 1) ? Bs0 : as_;
        const int base = ((j & 1) ? 65536 : 0) + (d * 2 + kh) * 16384;
        __builtin_amdgcn_global_load_lds((gp_t)(src + ko),
            (lp_t)(lds + base + dst0), 16, 0, 0);
        __builtin_amdgcn_global_load_lds((gp_t)(src + 128 * KDIM + ko),
            (lp_t)(lds + base + 8192 + dst0), 16, 0, 0);
    };

    const int c_colb = btn * 256 + wc * 64 + (lane & 31);
    float bvr[2];
#pragma unroll
    for (int n = 0; n < 2; ++n) bvr[n] = bias[(c_colb + n * 32) & 4095];

    f32x16 acc[4][2] = {};
    bf16x8 af[4], bfr[4];
    f32x4 pa = {}, pb = {};

    // Prologue: stage K-tile 0 + 3 half-tiles of K-tile 1 (gemm waves only).
    if (gw) {
        STAGE(A0, 0); STAGE(A0, 1); STAGE(A0, 2); STAGE(A0, 3);
        STAGE(A0, 4); STAGE(A0, 5); STAGE(A0, 6);
        VMCNT6();
    }
    BAR();

#pragma unroll 1
    for (int r = 0; r < 4; ++r) {
        const u16* Ar = A0 + (size_t)r * 512 * KDIM;
        const u16* An = (r < 3) ? (Ar + 512 * KDIM) : Ar;

        ITERF(Ar,  7, 0) ITERF(Ar, 15, 1) ITERF(Ar, 23, 2)
        ITERF(Ar, 31, 3) ITERF(Ar, 39, 4) ITERF(Ar, 47, 5)
        ITERF(Ar, 55, 6)

        // GATE: prep waves drain+arrive; gemm tid0 spins; then barrier.
        if (!gw) {
            if (r < 3) {
                VMCNT0();
                __threadfence();
                if (lane == 0)
                    __hip_atomic_fetch_add(&flags[1 + r], 1u, __ATOMIC_RELEASE,
                                           __HIP_MEMORY_SCOPE_AGENT);
            }
        } else if (tid == 0 && r < 3) {
            while (__hip_atomic_load(&flags[1 + r], __ATOMIC_ACQUIRE,
                                     __HIP_MEMORY_SCOPE_AGENT) < 512u)
                __builtin_amdgcn_s_sleep(8);
        }
        BAR();
        __threadfence();

        // Tail pair: stages slot 63 then next round's slots 0..6.
        PH (LOADB(0,0); LOADA(0,0,0); STAGE(Ar,63);, 0, 112)
        PH (LOADA(0,0,1);             STAGE(An,0);,  1, 114)
        PH (LOADB(0,1); LOADA(0,1,0); STAGE(An,1);,  0, 116)
        PHV(LOADA(0,1,1);             STAGE(An,2);,  1, 118)
        PH (LOADB(1,0); LOADA(1,0,0); STAGE(An,3);,  0, 120)
        PH (LOADA(1,0,1);             STAGE(An,4);,  1, 122)
        PH (LOADB(1,1); LOADA(1,1,0); STAGE(An,5);,  0, 124)
        PHV(LOADA(1,1,1);             STAGE(An,6);,  1, 126)

        // Epilogue (gemm waves only; no barriers).
        if (gw) {
            const int c_row0 = (btm0 + 2 * r) * 256 + wr * 128 + ((lane >> 5) & 1) * 4;
#pragma unroll
            for (int mi = 0; mi < 4; ++mi) {
#pragma unroll
                for (int n = 0; n < 2; ++n) {
                    f32x16 a = acc[mi][n];
#pragma unroll
                    for (int q = 0; q < 4; ++q) {
#pragma unroll
                        for (int rr = 0; rr < 4; ++rr) {
                            const int row = c_row0 + mi * 32 + q * 8 + rr;
                            __builtin_nontemporal_store(a[q * 4 + rr] + bvr[n],
                                &C[(size_t)row * NDIM + c_colb + n * 32]);
                        }
                    }
#pragma unroll
                    for (int z = 0; z < 16; ++z) acc[mi][n][z] = 0.f;
                }
            }
        }
    }
}

extern "C" void kernel_launch(void* const* d_in, const int* in_sizes, int n_in,
                              void* d_out, int out_size, void* d_ws, size_t ws_size,
                              hipStream_t stream) {
    const float* x      = (const float*)d_in[0];
    const float* values = (const float*)d_in[1];
    const float* bias   = (const float*)d_in[2];
    float* out = (float*)d_out;

    // ws: xg bf16 32 MB @ 0; vb bf16 8 MB @ 32 MB; flags @ 40 MB.
    u16* xg    = (u16*)d_ws;
    u16* vb    = (u16*)((char*)d_ws + ((size_t)32 << 20));
    u32* flags = (u32*)((char*)d_ws + ((size_t)40 << 20));

    hipMemsetAsync(flags, 0, 64, stream);
    fused_kernel<<<256, 640, 0, stream>>>(x, values, bias, xg, vb, flags, out);
}

// Round 14
// 207.358 us; speedup vs baseline: 6.8683x; 6.8683x over previous
//
#include <hip/hip_runtime.h>
#include <hip/hip_bf16.h>

// SrnmSpmm: out[b,s,n] = sum_k x[b,s,keep[k]] * values[n,k] + bias[n]
// keep: cols {8i, 8i+2} of D_IN=4096 -> K=1024. M = B*S = 16384, N = 4096.
//
// R14 = R11 (best measured: 205.5 us) with plain C stores (NT scalar stores
// inflated WRITE_SIZE ~25%; plain stores L2-combine the 128B segments).
// GEMM: persistent 256-block, 256x256 tile, 32x32x16 MFMA, BK=64 2-deep
// dbuf, vmcnt(6) schedule, st_16x32+bit4 swizzle (source-side + read-side).

#define M_TOTAL 16384
#define DIN     4096
#define KDIM    1024
#define NDIM    4096

typedef unsigned short u16;
typedef unsigned int   u32;
typedef __bf16 bf16x8 __attribute__((ext_vector_type(8)));
typedef float  f32x4  __attribute__((ext_vector_type(4)));
typedef float  f32x16 __attribute__((ext_vector_type(16)));

typedef const void __attribute__((address_space(1)))* gp_t;
typedef void __attribute__((address_space(3)))*       lp_t;

__device__ __forceinline__ u16 f2bf(float f) {
    u32 u = __float_as_uint(f);
    u += 0x7FFFu + ((u >> 16) & 1u);   // round-to-nearest-even
    return (u16)(u >> 16);
}
__device__ __forceinline__ u32 pack2(float a, float b) {
    return (u32)f2bf(a) | ((u32)f2bf(b) << 16);
}

// Pass 1: blocks [0,4096): compact x — each lane owns one 64B line (2 x
// 8-block): f32x4 @ +0 and @ +32B -> uint2 (kept cols 0,2). NT loads.
// Blocks [4096,6144): cast values, 8 floats/lane -> uint4. NT loads.
__global__ void prep_kernel(const float* __restrict__ x, uint2* __restrict__ xg2,
                            const float* __restrict__ vals, uint4* __restrict__ vb4) {
    const int tid = threadIdx.x;
    if (blockIdx.x < 4096) {
        int i = blockIdx.x * 256 + tid;
        const int stride = 4096 * 256;
#pragma unroll
        for (int it = 0; it < 4; ++it, i += stride) {
            const f32x4* p = (const f32x4*)(x + (size_t)i * 16);
            f32x4 f0 = __builtin_nontemporal_load(p);
            f32x4 f1 = __builtin_nontemporal_load(p + 2);
            xg2[i] = make_uint2(pack2(f0.x, f0.z), pack2(f1.x, f1.z));
        }
    } else {
        const int i = (blockIdx.x - 4096) * 256 + tid;
        const f32x4* p = (const f32x4*)(vals + (size_t)i * 8);
        f32x4 a = __builtin_nontemporal_load(p);
        f32x4 b = __builtin_nontemporal_load(p + 1);
        vb4[i] = make_uint4(pack2(a.x, a.y), pack2(a.z, a.w),
                            pack2(b.x, b.y), pack2(b.z, b.w));
    }
}

// ---------------- persistent 256x256 GEMM, 32x32x16 MFMA -------------------
// 512 threads = 8 waves (2M x 4N); wave tile 128x64 = 4m x 2n frags of 32x32.
// K-tile 64 = 2 K-halves (kh) x 2 K-steps (ks=16) each.
// Half-tile slot = 256 rows x 32 cols bf16 = 16 KiB = 2 gload_lds.
// LDS 128 KiB: A[dbuf][kh] @ (2d+kh)*16K, B @ +64K.
// Subtile [16r][32c] = 1 KiB; swizzle: byte ^= (row-bit3)<<5 ^ (row-bit4)<<4,
// applied on the pre-swizzled global SOURCE (gload dest linear) and on the
// ds_read address. Operand layout (32x32x16): row/col = lane&31,
// k = (lane>>5)*8 + j.  C/D: col = lane&31, row = (reg&3)+8*(reg>>2)+4*(lane>>5).

#define LDSA(d, kh) (((d) * 2 + (kh)) * 16384)
#define LDSB(d, kh) (65536 + ((d) * 2 + (kh)) * 16384)

#define LOADA(d, kh, mh) { _Pragma("unroll") \
    for (int mm = 0; mm < 2; ++mm) { _Pragma("unroll") \
    for (int ks = 0; ks < 2; ++ks) \
        af[mm * 2 + ks] = *(const bf16x8*)(lds + LDSA(d, kh) \
            + (wr * 8 + ((mh) * 2 + mm) * 2) * 1024 + fl_base \
            + (((ks << 5) + acol) ^ aswz)); } }

#define LOADB(d, kh) { _Pragma("unroll") \
    for (int nn = 0; nn < 2; ++nn) { _Pragma("unroll") \
    for (int ks = 0; ks < 2; ++ks) \
        bfr[nn * 2 + ks] = *(const bf16x8*)(lds + LDSB(d, kh) \
            + (wc * 4 + nn * 2) * 1024 + fl_base \
            + (((ks << 5) + acol) ^ aswz)); } }

#define MFMA8(mh) { \
    __builtin_amdgcn_s_setprio(1); \
    _Pragma("unroll") for (int mm = 0; mm < 2; ++mm) \
    _Pragma("unroll") for (int nn = 0; nn < 2; ++nn) \
    _Pragma("unroll") for (int ks = 0; ks < 2; ++ks) \
        acc[(mh) * 2 + mm][nn] = __builtin_amdgcn_mfma_f32_32x32x16_bf16( \
            af[mm * 2 + ks], bfr[nn * 2 + ks], acc[(mh) * 2 + mm][nn], 0, 0, 0); \
    __builtin_amdgcn_s_setprio(0); }

#define BAR() __builtin_amdgcn_s_barrier()
#define VMCNT6() asm volatile("s_waitcnt vmcnt(6)" ::: "memory")

__global__ __launch_bounds__(512, 2) void gemm_kernel(
    const u16* __restrict__ A, const u16* __restrict__ Bv,
    const float* __restrict__ bias, float* __restrict__ C)
{
    __shared__ __align__(1024) char lds[131072];

    const int tid  = threadIdx.x;
    const int lane = tid & 63;
    const int wid  = tid >> 6;
    const int wr   = wid >> 2;      // 0..1
    const int wc   = wid & 3;       // 0..3

    // Persistent mapping: XCD (bb&7) covers btm {8c..8c+7}; btn fixed/block.
    const int bb   = blockIdx.x;
    const int btm0 = (bb & 7) * 8 + (bb >> 7);
    const int btn  = (bb >> 3) & 15;

    // Staging source (pre-swizzled global addr; LDS dest linear).
    // Swizzle: elem ^= (tid-bit5 -> 16) ^ (tid-bit6 -> 8)  (byte bits 5,4).
    const int st_r0 = wid * 16 + (lane >> 2);
    const int st_ck = ((lane & 3) * 8) ^ ((tid & 32) >> 1) ^ ((tid & 64) >> 3);
    const u16* A0  = A  + (size_t)(btm0 * 256 + st_r0) * KDIM + st_ck;
    const u16* Bs0 = Bv + (size_t)(btn  * 256 + st_r0) * KDIM + st_ck;
    const int dst0 = tid * 16;

    // Fragment ds_read lane constants (rows = lane&31 span 2 subtiles).
    const int fl_base = (lane & 15) * 64 + ((lane >> 4) & 1) * 1024;
    const int aswz    = (((lane >> 3) & 1) << 5) ^ (((lane >> 4) & 1) << 4);
    const int acol    = ((lane >> 5) & 1) * 16;

    // half-tile slot s: kt=s>>2, j=s&3 (0=A.kh0,1=B.kh0,2=A.kh1,3=B.kh1)
    auto STAGE = [&](const u16* as_, int s) {
        const int kt = s >> 2, j = s & 3;
        const int d = kt & 1, kh = (j >> 1) & 1;
        const int ko = kt * 64 + kh * 32;
        const u16* src = (j & 1) ? Bs0 : as_;
        const int base = ((j & 1) ? 65536 : 0) + (d * 2 + kh) * 16384;
        __builtin_amdgcn_global_load_lds((gp_t)(src + ko),
            (lp_t)(lds + base + dst0), 16, 0, 0);
        __builtin_amdgcn_global_load_lds((gp_t)(src + 128 * KDIM + ko),
            (lp_t)(lds + base + 8192 + dst0), 16, 0, 0);
    };

    // bias (btn fixed): 2 scalars per lane (cols n*32 + lane&31).
    const int c_colb = btn * 256 + wc * 64 + (lane & 31);
    float bvr[2];
#pragma unroll
    for (int n = 0; n < 2; ++n) bvr[n] = bias[c_colb + n * 32];

    f32x16 acc[4][2] = {};
    bf16x8 af[4], bfr[4];

    // Prologue (once): stage K-tile 0 fully + 3 half-tiles of K-tile 1.
    STAGE(A0, 0); STAGE(A0, 1); STAGE(A0, 2); STAGE(A0, 3);
    STAGE(A0, 4); STAGE(A0, 5); STAGE(A0, 6);
    VMCNT6();
    BAR();

#pragma unroll 1
    for (int r = 0; r < 4; ++r) {
        const u16* Ar = A0 + (size_t)r * 512 * KDIM;
        const u16* An = (r < 3) ? (Ar + 512 * KDIM) : Ar;  // r=3: dummy re-stage

#pragma unroll 1
        for (int t = 0; t < 7; ++t) {
            const int s0 = 8 * t + 7;
            // ---- K-tile 2t (dbuf 0) ----
            LOADB(0, 0); LOADA(0, 0, 0); STAGE(Ar, s0);     BAR(); MFMA8(0); BAR();
            LOADA(0, 0, 1);              STAGE(Ar, s0 + 1); BAR(); MFMA8(1); BAR();
            LOADB(0, 1); LOADA(0, 1, 0); STAGE(Ar, s0 + 2); BAR(); MFMA8(0); BAR();
            LOADA(0, 1, 1);              STAGE(Ar, s0 + 3); BAR(); MFMA8(1);
            VMCNT6(); BAR();
            // ---- K-tile 2t+1 (dbuf 1) ----
            LOADB(1, 0); LOADA(1, 0, 0); STAGE(Ar, s0 + 4); BAR(); MFMA8(0); BAR();
            LOADA(1, 0, 1);              STAGE(Ar, s0 + 5); BAR(); MFMA8(1); BAR();
            LOADB(1, 1); LOADA(1, 1, 0); STAGE(Ar, s0 + 6); BAR(); MFMA8(0); BAR();
            LOADA(1, 1, 1);              STAGE(Ar, s0 + 7); BAR(); MFMA8(1);
            VMCNT6(); BAR();
        }
        // ---- tail: K-tiles 14 (dbuf 0) & 15 (dbuf 1); stage slots:
        // s63 (this tile) then n0..n6 (next tile).
        LOADB(0, 0); LOADA(0, 0, 0); STAGE(Ar, 63); BAR(); MFMA8(0); BAR();
        LOADA(0, 0, 1);              STAGE(An, 0);  BAR(); MFMA8(1); BAR();
        LOADB(0, 1); LOADA(0, 1, 0); STAGE(An, 1);  BAR(); MFMA8(0); BAR();
        LOADA(0, 1, 1);              STAGE(An, 2);  BAR(); MFMA8(1);
        VMCNT6(); BAR();
        LOADB(1, 0); LOADA(1, 0, 0); STAGE(An, 3);  BAR(); MFMA8(0); BAR();
        LOADA(1, 0, 1);              STAGE(An, 4);  BAR(); MFMA8(1); BAR();
        LOADB(1, 1); LOADA(1, 1, 0); STAGE(An, 5);  BAR(); MFMA8(0); BAR();
        LOADA(1, 1, 1);              STAGE(An, 6);  BAR(); MFMA8(1);
        VMCNT6(); BAR();

        // Epilogue tile r: PLAIN stores (L2 write-combines the 128B
        // segments; NT scalar stores inflated WRITE_SIZE ~25%).
        // C/D: col = lane&31, row = mi*32 + q*8 + rr + (lane>>5)*4.
        const int c_row0 = (btm0 + 2 * r) * 256 + wr * 128 + ((lane >> 5) & 1) * 4;
#pragma unroll
        for (int mi = 0; mi < 4; ++mi) {
#pragma unroll
            for (int n = 0; n < 2; ++n) {
                f32x16 a = acc[mi][n];
#pragma unroll
                for (int q = 0; q < 4; ++q) {
#pragma unroll
                    for (int rr = 0; rr < 4; ++rr) {
                        const int row = c_row0 + mi * 32 + q * 8 + rr;
                        C[(size_t)row * NDIM + c_colb + n * 32] = a[q * 4 + rr] + bvr[n];
                    }
                }
#pragma unroll
                for (int z = 0; z < 16; ++z) acc[mi][n][z] = 0.f;
            }
        }
    }
}

extern "C" void kernel_launch(void* const* d_in, const int* in_sizes, int n_in,
                              void* d_out, int out_size, void* d_ws, size_t ws_size,
                              hipStream_t stream) {
    const float* x      = (const float*)d_in[0];
    const float* values = (const float*)d_in[1];
    const float* bias   = (const float*)d_in[2];
    float* out = (float*)d_out;

    // ws: xg bf16 [16384][1024] = 32 MB @ 0; values bf16 [4096][1024] @ 32 MB
    u16* xg = (u16*)d_ws;
    u16* vb = (u16*)((char*)d_ws + ((size_t)32 << 20));

    prep_kernel<<<6144, 256, 0, stream>>>(x, (uint2*)xg, values, (uint4*)vb);
    gemm_kernel<<<256, 512, 0, stream>>>(xg, vb, bias, out);
}